// Round 5
// baseline (135.988 us; speedup 1.0000x reference)
//
#include <hip/hip_runtime.h>
#include <math.h>

// local_mixer via bf16 MFMA, swapped-QK^T, in-register softmax + permlane PV.
//   x:[8,256,256,64]f32  W:[192,64]f32  b:[192]f32  pos:[1,8,64,64]f32
//   out:[8192,64,64]f32
// 1 block = 1 window, 256 thr = 4 waves. heads=8, hc=8, seq=64.
// QKV: 16x16x32 (Q^T,K^T via W*X^T; V direct).
// QK^T swapped: S^T = K·Q^T (32x32x16, K=8 pad) -> lane-local row-sum.
// P never touches LDS: cvt_pk + v_permlane32_swap_b32 builds PV A-frags
// in-register; PV = 32x32x16 (cols 8..31 idle). exp2 with folded log2e.

typedef __attribute__((ext_vector_type(8)))  short bf16x8;
typedef __attribute__((ext_vector_type(4)))  float f32x4;
typedef __attribute__((ext_vector_type(16))) float f32x16;

__device__ inline unsigned int cvt_pk_bf16(float lo, float hi) {
    unsigned int r;
    asm("v_cvt_pk_bf16_f32 %0, %1, %2" : "=v"(r) : "v"(lo), "v"(hi));
    return r;
}
__device__ inline void permswap(unsigned int &a, unsigned int &b) {
    asm("v_permlane32_swap_b32 %0, %1" : "+v"(a), "+v"(b));
}
__device__ inline unsigned short f2bf(float f) {   // prep kernel only
    unsigned int u = __builtin_bit_cast(unsigned int, f);
    return (unsigned short)((u + 0x7FFFu + ((u >> 16) & 1u)) >> 16);
}
__device__ inline bf16x8 pack8(float4 a, float4 b) {
    union { unsigned int u[4]; bf16x8 v; } r;
    r.u[0] = cvt_pk_bf16(a.x, a.y);
    r.u[1] = cvt_pk_bf16(a.z, a.w);
    r.u[2] = cvt_pk_bf16(b.x, b.y);
    r.u[3] = cvt_pk_bf16(b.z, b.w);
    return r.v;
}

// ---- prep: pos -> f32 S^T-C-layout fragments, *log2e, into d_ws (128 KB) ----
// flat = (((h*2 + it)*2 + jt)*64 + lane)*16 + reg
__global__ __launch_bounds__(256) void prep_pos(const float* __restrict__ pos,
                                                float* __restrict__ pp)
{
    int flat = blockIdx.x * 256 + threadIdx.x;   // 0..32767
    int r  = flat & 15;
    int ln = (flat >> 4) & 63;
    int jt = (flat >> 10) & 1;
    int it = (flat >> 11) & 1;
    int h  = flat >> 12;
    int j = jt*32 + (r & 3) + 8*(r >> 2) + 4*(ln >> 5);   // S^T row
    int i = it*32 + (ln & 31);                            // S^T col
    pp[flat] = pos[(h*64 + i)*64 + j] * 1.4426950408889634f;
}

__global__ __launch_bounds__(256, 5) void lm_mfma(const float* __restrict__ x,
                                                  const float* __restrict__ Wq,
                                                  const float* __restrict__ bq,
                                                  const float* __restrict__ ppf,
                                                  float* __restrict__ out)
{
    // 32 KB LDS (5 blocks/CU). Chunk-swizzle: 8-bf16 chunk c8 of row r at c8^(r&7).
    __shared__ unsigned short sX [64*64];  // x window [n][c]
    __shared__ unsigned short sQ [64*64];  // q (scaled*log2e) [i][d]
    __shared__ unsigned short sK [64*64];  // k [j][d]
    __shared__ unsigned short sVT[64*64];  // v^T [c][j]

    const int tid = threadIdx.x;
    const int w   = blockIdx.x;
    const int ln  = tid & 63;
    const int wv  = tid >> 6;
    const int lr  = ln & 15;
    const int lg  = ln >> 4;

    const int bi = w >> 10, mm = w & 1023;
    const int mh = mm >> 5, mw = mm & 31;
    const float* xwin = x + ((size_t)(bi*256 + mh*8)*256 + mw*8)*64;

    // ---- stage x -> sX (bf16, swizzled) ----
    #pragma unroll
    for (int r = 0; r < 4; ++r) {
        const int f4 = tid + r*256;
        const int n  = f4 >> 4;
        const int c  = (f4 & 15) * 4;
        const float4 v = *(const float4*)(xwin + ((size_t)(n>>3)*256 + (n&7))*64 + c);
        uint2 u;
        u.x = cvt_pk_bf16(v.x, v.y);
        u.y = cvt_pk_bf16(v.z, v.w);
        *(uint2*)&sX[n*64 + (((c>>3) ^ (n&7))<<3) + (c&7)] = u;
    }

    // ---- W fragments: wave wv owns d-tiles {wv, wv+4, wv+8} ----
    bf16x8 wfrag[3][2];
    #pragma unroll
    for (int t = 0; t < 3; ++t) {
        const int d = (wv + 4*t)*16 + lr;
        #pragma unroll
        for (int kt = 0; kt < 2; ++kt) {
            const float* base = Wq + (size_t)d*64 + kt*32 + lg*8;
            wfrag[t][kt] = pack8(*(const float4*)base, *(const float4*)(base+4));
        }
    }
    const float qs = 0.35355339059327373f * 1.4426950408889634f;  // 8^-0.5 * log2e
    const float4 bqQr = *(const float4*)(bq       + wv*16 + lg*4);
    const float4 bqK  = *(const float4*)(bq + 64  + wv*16 + lg*4);
    const float  bqV  = bq[128 + wv*16 + lr];
    float4 bqQs;
    bqQs.x = bqQr.x*qs; bqQs.y = bqQr.y*qs; bqQs.z = bqQr.z*qs; bqQs.w = bqQr.w*qs;

    __syncthreads();

    // ---- QKV MFMAs (16x16x32) ----
    f32x4 aQ[4], aK[4], aV[4];
    #pragma unroll
    for (int nt = 0; nt < 4; ++nt) { aQ[nt]=0; aK[nt]=0; aV[nt]=0; }

    #pragma unroll
    for (int nt = 0; nt < 4; ++nt) {
        #pragma unroll
        for (int kt = 0; kt < 2; ++kt) {
            const int n  = lr + nt*16;
            const int c8 = lg + kt*4;
            const bf16x8 xf = *(const bf16x8*)&sX[n*64 + ((c8 ^ (n&7))<<3)];
            aQ[nt] = __builtin_amdgcn_mfma_f32_16x16x32_bf16(wfrag[0][kt], xf, aQ[nt], 0,0,0);
            aK[nt] = __builtin_amdgcn_mfma_f32_16x16x32_bf16(wfrag[1][kt], xf, aK[nt], 0,0,0);
            aV[nt] = __builtin_amdgcn_mfma_f32_16x16x32_bf16(xf, wfrag[2][kt], aV[nt], 0,0,0);
        }
    }

    #pragma unroll
    for (int nt = 0; nt < 4; ++nt) {
        const int n  = lr + nt*16;
        const int d0 = wv*16 + lg*4;
        const int qidx = n*64 + (((d0>>3) ^ (n&7))<<3) + (d0&7);
        uint2 uq, uk;
        uq.x = cvt_pk_bf16(fmaf(aQ[nt][0], qs, bqQs.x), fmaf(aQ[nt][1], qs, bqQs.y));
        uq.y = cvt_pk_bf16(fmaf(aQ[nt][2], qs, bqQs.z), fmaf(aQ[nt][3], qs, bqQs.w));
        uk.x = cvt_pk_bf16(aK[nt][0]+bqK.x, aK[nt][1]+bqK.y);
        uk.y = cvt_pk_bf16(aK[nt][2]+bqK.z, aK[nt][3]+bqK.w);
        *(uint2*)&sQ[qidx] = uq;
        *(uint2*)&sK[qidx] = uk;
        const int cc = wv*16 + lr;
        const int n0 = nt*16 + lg*4;
        uint2 uv;
        uv.x = cvt_pk_bf16(aV[nt][0]+bqV, aV[nt][1]+bqV);
        uv.y = cvt_pk_bf16(aV[nt][2]+bqV, aV[nt][3]+bqV);
        *(uint2*)&sVT[cc*64 + (((n0>>3) ^ (cc&7))<<3) + (n0&7)] = uv;
    }

    __syncthreads();

    // ---- attention: wave wv -> heads {2wv, 2wv+1}, i-tiles {0,1} ----
    const int cB  = ln & 31;     // PV output column (channel within head; <8 valid)
    const int hiB = ln >> 5;

    #pragma unroll 1
    for (int hh = 0; hh < 2; ++hh) {
        const int h = wv*2 + hh;

        // PV B-frags (32x32x16): lane holds col n=cB, k = 8*hiB + {0..7} = j in window
        bf16x8 vb[4];
        #pragma unroll
        for (int kt = 0; kt < 4; ++kt) {
            bf16x8 z = {};
            vb[kt] = z;
            if (cB < 8) {
                const int cc = h*8 + cB;
                const int ch = 2*kt + hiB;                 // chunk = (16kt+8hi)>>3
                vb[kt] = *(const bf16x8*)&sVT[cc*64 + ((ch ^ (cc&7))<<3)];
            }
        }

        #pragma unroll 1
        for (int it = 0; it < 2; ++it) {
            // C-init = pos fragments (f32, *log2e, pre-permuted): pure loads
            f32x16 C[2];
            #pragma unroll
            for (int jt = 0; jt < 2; ++jt)
                C[jt] = *(const f32x16*)(ppf + ((((h*2+it)*2 + jt)*64) + ln)*16);

            // swapped QK^T: S^T tiles = K · Q^T (K=8 of 16; hi lanes zero)
            bf16x8 qf = {}, kf0 = {}, kf1 = {};
            if (ln < 32) {
                const int i = it*32 + ln;
                qf  = *(const bf16x8*)&sQ[i*64 + ((h ^ (i&7))<<3)];
                kf0 = *(const bf16x8*)&sK[ln*64 + ((h ^ (ln&7))<<3)];
                const int j1 = 32 + ln;
                kf1 = *(const bf16x8*)&sK[j1*64 + ((h ^ (j1&7))<<3)];
            }
            C[0] = __builtin_amdgcn_mfma_f32_32x32x16_bf16(kf0, qf, C[0], 0,0,0);
            C[1] = __builtin_amdgcn_mfma_f32_32x32x16_bf16(kf1, qf, C[1], 0,0,0);

            // exp2 in place, tree row-sum (j is lane-local), normalize factor
            float s01, s23;
            {
                float t[8];
                #pragma unroll
                for (int jt = 0; jt < 2; ++jt)
                    #pragma unroll
                    for (int g = 0; g < 4; ++g) {
                        const int b = g*4;
                        C[jt][b+0] = __builtin_amdgcn_exp2f(C[jt][b+0]);
                        C[jt][b+1] = __builtin_amdgcn_exp2f(C[jt][b+1]);
                        C[jt][b+2] = __builtin_amdgcn_exp2f(C[jt][b+2]);
                        C[jt][b+3] = __builtin_amdgcn_exp2f(C[jt][b+3]);
                        t[jt*4+g] = (C[jt][b+0]+C[jt][b+1]) + (C[jt][b+2]+C[jt][b+3]);
                    }
                s01 = (t[0]+t[1]) + (t[2]+t[3]);
                s23 = (t[4]+t[5]) + (t[6]+t[7]);
            }
            const float sum = s01 + s23;
            const float tot = sum + __shfl_xor(sum, 32, 64);
            const float inv = __builtin_amdgcn_rcpf(tot);

            // PV: per K-window kt, build A-frag in-register (cvt_pk + permlane32_swap)
            f32x16 O = {};
            #pragma unroll
            for (int kt = 0; kt < 4; ++kt) {
                const int jt = kt >> 1;
                const int q8 = (kt & 1) * 8;
                unsigned int A0 = cvt_pk_bf16(C[jt][q8+0]*inv, C[jt][q8+1]*inv);
                unsigned int A1 = cvt_pk_bf16(C[jt][q8+2]*inv, C[jt][q8+3]*inv);
                unsigned int B0 = cvt_pk_bf16(C[jt][q8+4]*inv, C[jt][q8+5]*inv);
                unsigned int B1 = cvt_pk_bf16(C[jt][q8+6]*inv, C[jt][q8+7]*inv);
                permswap(A0, B0);
                permswap(A1, B1);
                union { unsigned int u[4]; bf16x8 v; } af;
                af.u[0] = A0; af.u[1] = A1; af.u[2] = B0; af.u[3] = B1;
                O = __builtin_amdgcn_mfma_f32_32x32x16_bf16(af.v, vb[kt], O, 0,0,0);
            }

            // store: lane holds col c=cB (<8), rows i = (r&3)+8(r>>2)+4*hiB
            if (cB < 8) {
                float* ob = out + (size_t)w*4096 + (size_t)(it*32)*64 + h*8 + cB;
                #pragma unroll
                for (int r = 0; r < 16; ++r) {
                    const int iloc = (r&3) + 8*(r>>2) + 4*hiB;
                    ob[(size_t)iloc*64] = O[r];
                }
            }
        }
    }
}

extern "C" void kernel_launch(void* const* d_in, const int* in_sizes, int n_in,
                              void* d_out, int out_size, void* d_ws, size_t ws_size,
                              hipStream_t stream)
{
    const float* x   = (const float*)d_in[0];
    const float* Wq  = (const float*)d_in[1];
    const float* bq  = (const float*)d_in[2];
    const float* pos = (const float*)d_in[3];
    float* out = (float*)d_out;
    float* pp  = (float*)d_ws;   // 128 KB

    hipLaunchKernelGGL(prep_pos, dim3(128), dim3(256), 0, stream, pos, pp);
    hipLaunchKernelGGL(lm_mfma, dim3(8192), dim3(256), 0, stream, x, Wq, bq, pp, out);
}